// Round 17
// baseline (296.407 us; speedup 1.0000x reference)
//
#include <hip/hip_runtime.h>

#define KTOP 1000
#define NB 1024
#define CAP 2048
#define PCAP 1024
#define HB 16              // hist/collect blocks per image (1024 threads each)
#define REL1 0.1f
#define REL2 0.05f

typedef unsigned long long u64;
typedef unsigned int u32;

__device__ __forceinline__ const float* pick_scores(const void* A, const void* B, int flag) {
    return flag ? (const float*)B : (const float*)A;   // flag=1 -> A is classes
}
__device__ __forceinline__ const int* pick_classes(const void* A, const void* B, int flag) {
    return flag ? (const int*)A : (const int*)B;
}

// flag=1 iff A looks like int class labels (all bit patterns < 256 over 256 probes).
__device__ __forceinline__ int block_flag256(const void* pA, int tid, int* ldsf) {
    if (tid == 0) *ldsf = 0;
    __syncthreads();
    if (tid < 256) {
        u32 v = ((const u32*)pA)[tid];
        u64 big = __ballot(v >= 256u);
        if ((tid & 63) == 0 && big) atomicOr(ldsf, 1);
    }
    __syncthreads();
    return *ldsf ? 0 : 1;
}

__device__ __forceinline__ int bucket_of(float v) {
    int bu = (int)(v * (float)NB);           // *1024 exact (pow2) -> monotone
    return bu < 0 ? 0 : (bu > NB - 1 ? NB - 1 : bu);
}

// ---- kernel 1: per-block partial histograms (plain stores); zero done[b] ----
__global__ __launch_bounds__(1024) void hist_kernel(const void* __restrict__ pA,
                                                    const void* __restrict__ pB, int N,
                                                    int* __restrict__ phist,   // [B][HB][NB]
                                                    int* __restrict__ done) {
    __shared__ int h[NB];
    __shared__ int ldsf;
    int b = blockIdx.y, blk = blockIdx.x;
    int t = threadIdx.x;
    int flag = block_flag256(pA, t, &ldsf);
    h[t] = 0;                                // NB == blockDim
    if (blk == 0 && t == 0) done[b] = 0;     // consumed by kernel 2 (stream-ordered)
    __syncthreads();
    const float* s = pick_scores(pA, pB, flag) + (size_t)b * N;
    const float4* s4 = (const float4*)s;
    int N4 = N >> 2;
    for (int i = blk * 1024 + t; i < N4; i += HB * 1024) {
        float4 v = s4[i];
        atomicAdd(&h[bucket_of(v.x)], 1);
        atomicAdd(&h[bucket_of(v.y)], 1);
        atomicAdd(&h[bucket_of(v.z)], 1);
        atomicAdd(&h[bucket_of(v.w)], 1);
    }
    for (int i = N4 * 4 + blk * 1024 + t; i < N; i += HB * 1024)
        atomicAdd(&h[bucket_of(s[i])], 1);
    __syncthreads();
    phist[((size_t)b * HB + blk) * NB + t] = h[t];
}

// ---- kernel 2: collect (exact-base, no global atomics) + last-block finish ----
__global__ __launch_bounds__(1024) void collectfinish_kernel(const void* __restrict__ pA,
                                                             const void* __restrict__ pB,
                                                             const float4* __restrict__ boxes,
                                                             int N,
                                                             const int* __restrict__ phist,
                                                             int* __restrict__ gbs,   // [B][NB]
                                                             int* __restrict__ gbe,   // [B][NB]
                                                             int* __restrict__ cnt,   // [B]
                                                             u64* __restrict__ ckey,  // [B][CAP]
                                                             float4* __restrict__ cbox,
                                                             int* __restrict__ ccls,
                                                             int* __restrict__ done,  // [B]
                                                             float* __restrict__ out, int B) {
    // ---- collect-phase LDS ----
    __shared__ int hh[NB];
    __shared__ int bb[NB];
    __shared__ int bcL[NB];
    __shared__ int csum[256];
    __shared__ int ldsf, scut, sdone;
    // ---- finish-phase LDS ----
    __shared__ u64 uni[CAP];        // key[] -> myPos/pairs/sorted (disjoint lifetimes)
    __shared__ int gbsL[NB];
    __shared__ int gbeL[NB];
    __shared__ float4 sbox[KTOP];
    __shared__ float sarea[KTOP];
    __shared__ float sscore[KTOP];
    __shared__ int scls[KTOP];
    __shared__ short items[KTOP];
    __shared__ int clsCnt[128];
    __shared__ int clsStart[128];
    __shared__ u64 keepw[16];
    __shared__ int firstIdx[128];
    __shared__ int wtot[16];
    __shared__ int npair;

    int b = blockIdx.y, blk = blockIdx.x;
    int tid = threadIdx.x;
    int lane = tid & 63;
    int wid = tid >> 6;
    int flag = block_flag256(pA, tid, &ldsf);
    const int* classes = pick_classes(pA, pB, flag);

    {   // sum partials; simultaneously accumulate this block's exclusive prefix
        const int* src = phist + (size_t)b * HB * NB;
        int acc = 0, excl = 0;
#pragma unroll
        for (int k = 0; k < HB; ++k) {
            int v = src[k * NB + tid];       // coalesced
            acc += v;
            if (k < blk) excl += v;
        }
        hh[tid] = acc;
        bb[tid] = excl;
        bcL[tid] = 0;
    }
    __syncthreads();
    if (tid < 256) {   // group sums, descending groups of 4
        int base = NB - 1 - tid * 4;
        csum[tid] = hh[base] + hh[base - 1] + hh[base - 2] + hh[base - 3];
    }
    __syncthreads();
    if (tid == 0) {
        // cutoff: bucket of the KTOP-th largest score (verbatim proven logic)
        int cum = 0, cut = 0;
        for (int u = 0; u < 256; ++u) {
            if (cum + csum[u] >= KTOP) {
                for (int k = 0; k < 4; ++k) {
                    cum += hh[NB - 1 - u * 4 - k];
                    if (cum >= KTOP) { cut = NB - 1 - u * 4 - k; break; }
                }
                break;
            }
            cum += csum[u];
        }
        scut = cut;
        int run = 0;   // in-place exclusive prefix over groups (descending)
        for (int g = 0; g < 256; ++g) { int c = csum[g]; csum[g] = run; run += c; }
    }
    __syncthreads();
    if (tid < 256) {   // bb[bu] += bstart[bu] (keys in strictly-higher buckets)
        int gp = csum[tid];
        int base = NB - 1 - tid * 4;
        int h0 = hh[base], h1 = hh[base - 1], h2 = hh[base - 2];
        bb[base]     += gp;
        bb[base - 1] += gp + h0;
        bb[base - 2] += gp + h0 + h1;
        bb[base - 3] += gp + h0 + h1 + h2;
    }
    __syncthreads();
    int cut = scut;

    if (blk == 0) {     // block 0: excl==0 so bb == bstart -> export ranges + total
        gbs[(size_t)b * NB + tid] = bb[tid];
        gbe[(size_t)b * NB + tid] = bb[tid] + hh[tid];
        if (tid == 0) cnt[b] = bb[cut] + hh[cut];
    }

    {   // candidate write pass (LDS atomics only; scattered gathers hide in stream)
        const float* s = pick_scores(pA, pB, flag) + (size_t)b * N;
        const float4* s4 = (const float4*)s;
        int N4 = N >> 2;
        u64* kb = ckey + (size_t)b * CAP;
        float4* xb = cbox + (size_t)b * CAP;
        int* lb = ccls + (size_t)b * CAP;
        for (int i = blk * 1024 + tid; i < N4; i += HB * 1024) {
            float4 v = s4[i];
            float vv[4] = {v.x, v.y, v.z, v.w};
#pragma unroll
            for (int k = 0; k < 4; ++k) {
                int bu = bucket_of(vv[k]);
                if (bu >= cut) {
                    int pos = bb[bu] + atomicAdd(&bcL[bu], 1);
                    if (pos < CAP) {
                        int idx = i * 4 + k;
                        kb[pos] = ((u64)__float_as_uint(vv[k]) << 32) | (u32)(~(u32)idx);
                        xb[pos] = boxes[(size_t)b * N + idx];
                        lb[pos] = classes[(size_t)b * N + idx];
                    }
                }
            }
        }
        for (int i = N4 * 4 + blk * 1024 + tid; i < N; i += HB * 1024) {
            float v = s[i];
            int bu = bucket_of(v);
            if (bu >= cut) {
                int pos = bb[bu] + atomicAdd(&bcL[bu], 1);
                if (pos < CAP) {
                    kb[pos] = ((u64)__float_as_uint(v) << 32) | (u32)(~(u32)i);
                    xb[pos] = boxes[(size_t)b * N + i];
                    lb[pos] = classes[(size_t)b * N + i];
                }
            }
        }
    }

    // ---- last-block handoff: device-scope release -> counter -> acquire ----
    __threadfence();                           // release this block's writes
    __syncthreads();
    if (tid == 0) sdone = (atomicAdd(&done[b], 1) == HB - 1) ? 1 : 0;
    __syncthreads();
    if (!sdone) return;
    __threadfence();                           // acquire all peers' writes

    // ================= finish phase (verbatim R16 logic) =================
    u64* key    = uni;
    int* myPos  = (int*)uni;
    u32* pairs  = (u32*)uni;
    u32* sorted = ((u32*)uni) + PCAP;

    if (tid < 128) { clsCnt[tid] = 0; firstIdx[tid] = 0x7fffffff; }
    if (tid == 0) npair = 0;
    gbsL[tid] = gbs[(size_t)b * NB + tid];
    gbeL[tid] = gbe[(size_t)b * NB + tid];
    int M = cnt[b]; if (M > CAP) M = CAP;
    const u64* kb = ckey + (size_t)b * CAP;
    for (int e = tid; e < M; e += 1024) key[e] = kb[e];
    __syncthreads();

    // bucket-local rank in LDS (global rank = bstart + within-bucket count)
    for (int c = tid; c < M; c += 1024) {
        u64 k = key[c];
        float sc = __uint_as_float((u32)(k >> 32));
        int bu = bucket_of(sc);
        int st = gbsL[bu];
        int en = gbeL[bu]; if (en > CAP) en = CAP;
        int r = st;
        for (int j = st; j < en; ++j) r += (key[j] > k);
        if (r < KTOP) {
            sscore[r] = sc;
            scls[r] = ccls[(size_t)b * CAP + c];
            sbox[r] = cbox[(size_t)b * CAP + c];
        }
    }
    __syncthreads();   // key[] dead; uni reused

    if (tid < KTOP) {
        float4 bx = sbox[tid];
        sarea[tid] = (bx.z - bx.x) * (bx.w - bx.y);
        myPos[tid] = atomicAdd(&clsCnt[scls[tid] & 127], 1);
    }
    __syncthreads();
    if (tid == 0) {
        int acc = 0;
        for (int c = 0; c < 128; ++c) { clsStart[c] = acc; acc += clsCnt[c]; }
    }
    __syncthreads();
    if (tid < KTOP) items[clsStart[scls[tid] & 127] + myPos[tid]] = (short)tid;
    __syncthreads();   // myPos dead

    if (tid < KTOP) {   // pair finding within class buckets (avg ~12.5 entries)
        int i = tid;
        float4 bi = sbox[i];
        float ai = sarea[i];
        int ci = scls[i];
        int cb2 = ci & 127, st = clsStart[cb2], n = clsCnt[cb2];
        for (int q = 0; q < n; ++q) {
            int j = items[st + q];
            if (j <= i || scls[j] != ci) continue;
            float4 bj = sbox[j];
            float xx1 = fmaxf(bi.x, bj.x);
            float yy1 = fmaxf(bi.y, bj.y);
            float xx2 = fminf(bi.z, bj.z);
            float yy2 = fminf(bi.w, bj.w);
            float ww = fmaxf(xx2 - xx1, 0.f);
            float hh2 = fmaxf(yy2 - yy1, 0.f);
            float inter = ww * hh2;
            float iou = inter / (ai + sarea[j] - inter);   // exact reference op order
            if (iou > 0.5f) {
                int p = atomicAdd(&npair, 1);
                if (p < PCAP) pairs[p] = ((u32)i << 10) | (u32)j;
            }
        }
    }
    __syncthreads();

    int P = npair; if (P > PCAP) P = PCAP;
    if (tid < P) {                      // rank-sort ascending; keys unique
        u32 k = pairs[tid];
        int rr = 0;
        for (int q = 0; q < P; ++q) rr += (pairs[q] < k);
        sorted[rr] = k;
    }
    __syncthreads();

    if (wid == 0) {   // greedy walk over sorted pairs; lane l<16 owns sup word l
        u64 sup = 0;
        for (int p = 0; p < P; ++p) {
            u32 k = sorted[p];
            int i = k >> 10;
            u64 supw = __shfl(sup, i >> 6);
            if (((supw >> (i & 63)) & 1ull) == 0ull) {   // i kept -> suppress j
                int j = (int)(k & 1023u);
                if (lane == (j >> 6)) sup |= 1ull << (j & 63);
            }
        }
        if (lane < 16) keepw[lane] = ~sup;
    }
    __syncthreads();

    float s0 = sscore[0];   // index 0 never suppressed; scores descending

    for (int i = tid; i < KTOP; i += 1024) {
        bool kp = (keepw[i >> 6] >> (i & 63)) & 1ull;
        if (kp && sscore[i] >= REL1 * s0) atomicMin(&firstIdx[scls[i] & 127], i);
    }
    __syncthreads();

    bool fin = false;
    if (tid < KTOP) {
        bool kp = (keepw[tid >> 6] >> (tid & 63)) & 1ull;
        bool v3 = kp && (sscore[tid] >= REL1 * s0);
        if (v3) {
            int f = firstIdx[scls[tid] & 127];
            bool del = (f < tid) && (sscore[tid] < REL2 * sscore[f]);
            fin = !del;
        }
    }
    u64 m = __ballot(fin);
    if (lane == 0) wtot[wid] = __popcll(m);
    __syncthreads();
    int prefix = 0, V = 0;
    for (int k = 0; k < 16; ++k) { int c = wtot[k]; if (k < wid) prefix += c; V += c; }
    int rank = prefix + __popcll(m & ((1ull << lane) - 1ull));

    float* ob = out;                          // boxes  [B,100,4]
    float* oc = out + (size_t)B * 400;        // classes[B,100] (as float)
    float* os = out + (size_t)B * 500;        // scores [B,100]
    if (fin && rank < 100) {
        int o = b * 100 + rank;
        float4 bx = sbox[tid];
        ob[o * 4 + 0] = bx.x;
        ob[o * 4 + 1] = bx.y;
        ob[o * 4 + 2] = bx.z;
        ob[o * 4 + 3] = bx.w;
        oc[o] = (float)scls[tid];
        os[o] = sscore[tid];
    }
    int Vc = V < 100 ? V : 100;
    if (tid >= Vc && tid < 100) {
        int o = b * 100 + tid;
        ob[o * 4 + 0] = 0.f;
        ob[o * 4 + 1] = 0.f;
        ob[o * 4 + 2] = 0.f;
        ob[o * 4 + 3] = 0.f;
        oc[o] = -1.f;
        os[o] = 0.f;
    }
}

extern "C" void kernel_launch(void* const* d_in, const int* in_sizes, int n_in,
                              void* d_out, int out_size, void* d_ws, size_t ws_size,
                              hipStream_t stream) {
    (void)n_in; (void)ws_size;
    float* out = (float*)d_out;
    int B = out_size / 600;          // 100*(4+1+1) per image

    // identify boxes input purely from sizes (4N vs N); robust to any permutation
    int ib = 0;
    for (int i = 1; i < 3; ++i) if (in_sizes[i] > in_sizes[ib]) ib = i;
    int o1 = -1, o2 = -1;
    for (int i = 0; i < 3; ++i) if (i != ib) { if (o1 < 0) o1 = i; else o2 = i; }
    int N = in_sizes[o1] / B;
    const float4* boxes = (const float4*)d_in[ib];
    const void* pA = d_in[o1];
    const void* pB = d_in[o2];

    char* ws = (char*)d_ws;
    size_t off = 0;
    auto alloc = [&](size_t bytes) { size_t r = off; off += (bytes + 255) & ~(size_t)255; return r; };
    size_t ph_off   = alloc((size_t)B * HB * NB * 4);     // 2 MB
    size_t bs_off   = alloc((size_t)B * NB * 4);          // gbs
    size_t be_off   = alloc((size_t)B * NB * 4);          // gbe
    size_t cnt_off  = alloc((size_t)B * 4);
    size_t dn_off   = alloc((size_t)B * 4);               // done counters
    size_t kk_off   = alloc((size_t)B * CAP * 8);         // ckey
    size_t xb_off   = alloc((size_t)B * CAP * 16);        // cbox
    size_t lb_off   = alloc((size_t)B * CAP * 4);         // ccls

    int* phist  = (int*)(ws + ph_off);
    int* gbs    = (int*)(ws + bs_off);
    int* gbe    = (int*)(ws + be_off);
    int* cnt    = (int*)(ws + cnt_off);
    int* done   = (int*)(ws + dn_off);
    u64* ckey   = (u64*)(ws + kk_off);
    float4* cbox = (float4*)(ws + xb_off);
    int* ccls   = (int*)(ws + lb_off);

    hist_kernel<<<dim3(HB, B), 1024, 0, stream>>>(pA, pB, N, phist, done);
    collectfinish_kernel<<<dim3(HB, B), 1024, 0, stream>>>(pA, pB, boxes, N, phist,
                                                           gbs, gbe, cnt, ckey, cbox, ccls,
                                                           done, out, B);
}

// Round 18
// 43.905 us; speedup vs baseline: 6.7510x; 6.7510x over previous
//
#include <hip/hip_runtime.h>

#define KTOP 1000
#define NB 1024
#define CAP 2048
#define PCAP 1024
#define HB 16              // hist/collect blocks per image (1024 threads each)
#define REL1 0.1f
#define REL2 0.05f

typedef unsigned long long u64;
typedef unsigned int u32;

__device__ __forceinline__ const float* pick_scores(const void* A, const void* B, int flag) {
    return flag ? (const float*)B : (const float*)A;   // flag=1 -> A is classes
}
__device__ __forceinline__ const int* pick_classes(const void* A, const void* B, int flag) {
    return flag ? (const int*)A : (const int*)B;
}

// flag=1 iff A looks like int class labels (all bit patterns < 256 over 256 probes).
__device__ __forceinline__ int block_flag256(const void* pA, int tid, int* ldsf) {
    if (tid == 0) *ldsf = 0;
    __syncthreads();
    if (tid < 256) {
        u32 v = ((const u32*)pA)[tid];
        u64 big = __ballot(v >= 256u);
        if ((tid & 63) == 0 && big) atomicOr(ldsf, 1);
    }
    __syncthreads();
    return *ldsf ? 0 : 1;
}

__device__ __forceinline__ int bucket_of(float v) {
    int bu = (int)(v * (float)NB);           // *1024 exact (pow2) -> monotone
    return bu < 0 ? 0 : (bu > NB - 1 ? NB - 1 : bu);
}

// ---- kernel 1: per-block partial histograms (plain stores) ----
__global__ __launch_bounds__(1024) void hist_kernel(const void* __restrict__ pA,
                                                    const void* __restrict__ pB, int N,
                                                    int* __restrict__ phist) {  // [B][HB][NB]
    __shared__ int h[NB];
    __shared__ int ldsf;
    int b = blockIdx.y, blk = blockIdx.x;
    int t = threadIdx.x;
    int flag = block_flag256(pA, t, &ldsf);
    h[t] = 0;                                // NB == blockDim
    __syncthreads();
    const float* s = pick_scores(pA, pB, flag) + (size_t)b * N;
    const float4* s4 = (const float4*)s;
    int N4 = N >> 2;
    for (int i = blk * 1024 + t; i < N4; i += HB * 1024) {
        float4 v = s4[i];
        atomicAdd(&h[bucket_of(v.x)], 1);
        atomicAdd(&h[bucket_of(v.y)], 1);
        atomicAdd(&h[bucket_of(v.z)], 1);
        atomicAdd(&h[bucket_of(v.w)], 1);
    }
    for (int i = N4 * 4 + blk * 1024 + t; i < N; i += HB * 1024)
        atomicAdd(&h[bucket_of(s[i])], 1);
    __syncthreads();
    phist[((size_t)b * HB + blk) * NB + t] = h[t];
}

// ---- kernel 2: exact-base bucket-grouped collect; also gathers box+class ----
// blockBase[bu] = bstart[bu] + sum_{k<blk} phist[b][k][bu]; within-block order via
// LDS counters (no global atomics). Scattered boxes/classes loads happen HERE at
// full occupancy (32 waves/CU) where they hide under the score stream.
__global__ __launch_bounds__(1024) void collect_kernel(const void* __restrict__ pA,
                                                       const void* __restrict__ pB,
                                                       const float4* __restrict__ boxes, int N,
                                                       const int* __restrict__ phist,
                                                       int* __restrict__ gbs,   // [B][NB]
                                                       int* __restrict__ gbe,   // [B][NB]
                                                       int* __restrict__ cnt,   // [B] total M
                                                       u64* __restrict__ ckey,  // [B][CAP]
                                                       float4* __restrict__ cbox,// [B][CAP]
                                                       int* __restrict__ ccls) { // [B][CAP]
    __shared__ int hh[NB];       // full per-image histogram
    __shared__ int bb[NB];       // this block's base per bucket
    __shared__ int bcL[NB];      // within-block LDS counters
    __shared__ int csum[256];
    __shared__ int ldsf, scut;
    int b = blockIdx.y, blk = blockIdx.x;
    int t = threadIdx.x;
    int flag = block_flag256(pA, t, &ldsf);
    const int* classes = pick_classes(pA, pB, flag);

    {   // sum partials; simultaneously accumulate this block's exclusive prefix
        const int* src = phist + (size_t)b * HB * NB;
        int acc = 0, excl = 0;
#pragma unroll
        for (int k = 0; k < HB; ++k) {
            int v = src[k * NB + t];         // coalesced
            acc += v;
            if (k < blk) excl += v;
        }
        hh[t] = acc;
        bb[t] = excl;
        bcL[t] = 0;
    }
    __syncthreads();
    if (t < 256) {   // group sums, descending groups of 4
        int base = NB - 1 - t * 4;
        csum[t] = hh[base] + hh[base - 1] + hh[base - 2] + hh[base - 3];
    }
    __syncthreads();
    if (t == 0) {
        // cutoff: bucket of the KTOP-th largest score (verbatim proven logic)
        int cum = 0, cut = 0;
        for (int u = 0; u < 256; ++u) {
            if (cum + csum[u] >= KTOP) {
                for (int k = 0; k < 4; ++k) {
                    cum += hh[NB - 1 - u * 4 - k];
                    if (cum >= KTOP) { cut = NB - 1 - u * 4 - k; break; }
                }
                break;
            }
            cum += csum[u];
        }
        scut = cut;
        int run = 0;   // in-place exclusive prefix over groups (descending)
        for (int g = 0; g < 256; ++g) { int c = csum[g]; csum[g] = run; run += c; }
    }
    __syncthreads();
    if (t < 256) {   // bb[bu] += bstart[bu] (keys in strictly-higher buckets)
        int gp = csum[t];
        int base = NB - 1 - t * 4;
        int h0 = hh[base], h1 = hh[base - 1], h2 = hh[base - 2];
        bb[base]     += gp;
        bb[base - 1] += gp + h0;
        bb[base - 2] += gp + h0 + h1;
        bb[base - 3] += gp + h0 + h1 + h2;
    }
    __syncthreads();
    int cut = scut;

    if (blk == 0) {     // block 0: excl==0 so bb == bstart -> export ranges + total
        gbs[(size_t)b * NB + t] = bb[t];
        gbe[(size_t)b * NB + t] = bb[t] + hh[t];
        if (t == 0) cnt[b] = bb[cut] + hh[cut];
    }

    const float* s = pick_scores(pA, pB, flag) + (size_t)b * N;
    const float4* s4 = (const float4*)s;
    int N4 = N >> 2;
    u64* kb = ckey + (size_t)b * CAP;
    float4* xb = cbox + (size_t)b * CAP;
    int* lb = ccls + (size_t)b * CAP;
    for (int i = blk * 1024 + t; i < N4; i += HB * 1024) {
        float4 v = s4[i];
        float vv[4] = {v.x, v.y, v.z, v.w};
#pragma unroll
        for (int k = 0; k < 4; ++k) {
            int bu = bucket_of(vv[k]);
            if (bu >= cut) {
                int pos = bb[bu] + atomicAdd(&bcL[bu], 1);   // LDS atomic only
                if (pos < CAP) {
                    int idx = i * 4 + k;
                    kb[pos] = ((u64)__float_as_uint(vv[k]) << 32) | (u32)(~(u32)idx);
                    xb[pos] = boxes[(size_t)b * N + idx];
                    lb[pos] = classes[(size_t)b * N + idx];
                }
            }
        }
    }
    for (int i = N4 * 4 + blk * 1024 + t; i < N; i += HB * 1024) {
        float v = s[i];
        int bu = bucket_of(v);
        if (bu >= cut) {
            int pos = bb[bu] + atomicAdd(&bcL[bu], 1);
            if (pos < CAP) {
                kb[pos] = ((u64)__float_as_uint(v) << 32) | (u32)(~(u32)i);
                xb[pos] = boxes[(size_t)b * N + i];
                lb[pos] = classes[(size_t)b * N + i];
            }
        }
    }
}

// ---- kernel 3: LDS bucket-local rank -> NMS -> output (all reads contiguous) ----
__global__ __launch_bounds__(1024) void finish_kernel(const int* __restrict__ cnt,
                                                      const u64* __restrict__ ckey,
                                                      const float4* __restrict__ cbox,
                                                      const int* __restrict__ ccls,
                                                      const int* __restrict__ gbs,
                                                      const int* __restrict__ gbe,
                                                      float* __restrict__ out, int B) {
    __shared__ u64 uni[CAP];        // phase0: key[]; later myPos/pairs/sorted
    __shared__ int gbsL[NB];
    __shared__ int gbeL[NB];
    __shared__ float4 sbox[KTOP];
    __shared__ float sarea[KTOP];
    __shared__ float sscore[KTOP];
    __shared__ int scls[KTOP];
    __shared__ short items[KTOP];
    __shared__ int clsCnt[128];
    __shared__ int clsStart[128];
    __shared__ u64 keepw[16];
    __shared__ int firstIdx[128];
    __shared__ int wtot[16];
    __shared__ int npair;

    u64* key    = uni;
    int* myPos  = (int*)uni;
    u32* pairs  = (u32*)uni;
    u32* sorted = ((u32*)uni) + PCAP;

    int b = blockIdx.x;
    int tid = threadIdx.x;
    int lane = tid & 63;
    int wid = tid >> 6;

    if (tid < 128) { clsCnt[tid] = 0; firstIdx[tid] = 0x7fffffff; }
    if (tid == 0) npair = 0;
    gbsL[tid] = gbs[(size_t)b * NB + tid];      // contiguous
    gbeL[tid] = gbe[(size_t)b * NB + tid];
    int M = cnt[b]; if (M > CAP) M = CAP;
    const u64* kb = ckey + (size_t)b * CAP;
    for (int e = tid; e < M; e += 1024) key[e] = kb[e];   // contiguous
    __syncthreads();

    // phase 0: bucket-local rank in LDS (global rank = bstart + within-bucket count)
    for (int c = tid; c < M; c += 1024) {
        u64 k = key[c];
        float sc = __uint_as_float((u32)(k >> 32));
        int bu = bucket_of(sc);
        int st = gbsL[bu];
        int en = gbeL[bu]; if (en > CAP) en = CAP;
        int r = st;
        for (int j = st; j < en; ++j) r += (key[j] > k);   // LDS, ~98 iters avg
        if (r < KTOP) {
            sscore[r] = sc;
            scls[r] = ccls[(size_t)b * CAP + c];           // contiguous in c
            sbox[r] = cbox[(size_t)b * CAP + c];
        }
    }
    __syncthreads();   // key[] dead; uni reused

    // class bucketing
    if (tid < KTOP) {
        float4 bx = sbox[tid];
        sarea[tid] = (bx.z - bx.x) * (bx.w - bx.y);
        myPos[tid] = atomicAdd(&clsCnt[scls[tid] & 127], 1);
    }
    __syncthreads();
    if (tid == 0) {
        int acc = 0;
        for (int c = 0; c < 128; ++c) { clsStart[c] = acc; acc += clsCnt[c]; }
    }
    __syncthreads();
    if (tid < KTOP) items[clsStart[scls[tid] & 127] + myPos[tid]] = (short)tid;
    __syncthreads();   // myPos dead

    // pair finding within class buckets (avg ~12.5 entries)
    if (tid < KTOP) {
        int i = tid;
        float4 bi = sbox[i];
        float ai = sarea[i];
        int ci = scls[i];
        int cb2 = ci & 127, st = clsStart[cb2], n = clsCnt[cb2];
        for (int q = 0; q < n; ++q) {
            int j = items[st + q];
            if (j <= i || scls[j] != ci) continue;
            float4 bj = sbox[j];
            float xx1 = fmaxf(bi.x, bj.x);
            float yy1 = fmaxf(bi.y, bj.y);
            float xx2 = fminf(bi.z, bj.z);
            float yy2 = fminf(bi.w, bj.w);
            float ww = fmaxf(xx2 - xx1, 0.f);
            float hh2 = fmaxf(yy2 - yy1, 0.f);
            float inter = ww * hh2;
            float iou = inter / (ai + sarea[j] - inter);   // exact reference op order
            if (iou > 0.5f) {
                int p = atomicAdd(&npair, 1);
                if (p < PCAP) pairs[p] = ((u32)i << 10) | (u32)j;
            }
        }
    }
    __syncthreads();

    int P = npair; if (P > PCAP) P = PCAP;
    if (tid < P) {                      // rank-sort ascending; keys unique
        u32 k = pairs[tid];
        int rr = 0;
        for (int q = 0; q < P; ++q) rr += (pairs[q] < k);
        sorted[rr] = k;
    }
    __syncthreads();

    // greedy walk over sorted pairs; wave 0, lane l<16 owns sup word l
    if (wid == 0) {
        u64 sup = 0;
        for (int p = 0; p < P; ++p) {
            u32 k = sorted[p];
            int i = k >> 10;
            u64 supw = __shfl(sup, i >> 6);
            if (((supw >> (i & 63)) & 1ull) == 0ull) {   // i kept -> suppress j
                int j = (int)(k & 1023u);
                if (lane == (j >> 6)) sup |= 1ull << (j & 63);
            }
        }
        if (lane < 16) keepw[lane] = ~sup;
    }
    __syncthreads();

    float s0 = sscore[0];   // index 0 never suppressed; scores descending

    for (int i = tid; i < KTOP; i += 1024) {
        bool kp = (keepw[i >> 6] >> (i & 63)) & 1ull;
        if (kp && sscore[i] >= REL1 * s0) atomicMin(&firstIdx[scls[i] & 127], i);
    }
    __syncthreads();

    bool fin = false;
    if (tid < KTOP) {
        bool kp = (keepw[tid >> 6] >> (tid & 63)) & 1ull;
        bool v3 = kp && (sscore[tid] >= REL1 * s0);
        if (v3) {
            int f = firstIdx[scls[tid] & 127];
            bool del = (f < tid) && (sscore[tid] < REL2 * sscore[f]);
            fin = !del;
        }
    }
    u64 m = __ballot(fin);
    if (lane == 0) wtot[wid] = __popcll(m);
    __syncthreads();
    int prefix = 0, V = 0;
    for (int k = 0; k < 16; ++k) { int c = wtot[k]; if (k < wid) prefix += c; V += c; }
    int rank = prefix + __popcll(m & ((1ull << lane) - 1ull));

    float* ob = out;                          // boxes  [B,100,4]
    float* oc = out + (size_t)B * 400;        // classes[B,100] (as float)
    float* os = out + (size_t)B * 500;        // scores [B,100]
    if (fin && rank < 100) {
        int o = b * 100 + rank;
        float4 bx = sbox[tid];
        ob[o * 4 + 0] = bx.x;
        ob[o * 4 + 1] = bx.y;
        ob[o * 4 + 2] = bx.z;
        ob[o * 4 + 3] = bx.w;
        oc[o] = (float)scls[tid];
        os[o] = sscore[tid];
    }
    int Vc = V < 100 ? V : 100;
    if (tid >= Vc && tid < 100) {
        int o = b * 100 + tid;
        ob[o * 4 + 0] = 0.f;
        ob[o * 4 + 1] = 0.f;
        ob[o * 4 + 2] = 0.f;
        ob[o * 4 + 3] = 0.f;
        oc[o] = -1.f;
        os[o] = 0.f;
    }
}

extern "C" void kernel_launch(void* const* d_in, const int* in_sizes, int n_in,
                              void* d_out, int out_size, void* d_ws, size_t ws_size,
                              hipStream_t stream) {
    (void)n_in; (void)ws_size;
    float* out = (float*)d_out;
    int B = out_size / 600;          // 100*(4+1+1) per image

    // identify boxes input purely from sizes (4N vs N); robust to any permutation
    int ib = 0;
    for (int i = 1; i < 3; ++i) if (in_sizes[i] > in_sizes[ib]) ib = i;
    int o1 = -1, o2 = -1;
    for (int i = 0; i < 3; ++i) if (i != ib) { if (o1 < 0) o1 = i; else o2 = i; }
    int N = in_sizes[o1] / B;
    const float4* boxes = (const float4*)d_in[ib];
    const void* pA = d_in[o1];
    const void* pB = d_in[o2];

    char* ws = (char*)d_ws;
    size_t off = 0;
    auto alloc = [&](size_t bytes) { size_t r = off; off += (bytes + 255) & ~(size_t)255; return r; };
    size_t ph_off   = alloc((size_t)B * HB * NB * 4);     // 2 MB
    size_t bs_off   = alloc((size_t)B * NB * 4);          // gbs
    size_t be_off   = alloc((size_t)B * NB * 4);          // gbe
    size_t cnt_off  = alloc((size_t)B * 4);
    size_t kk_off   = alloc((size_t)B * CAP * 8);         // ckey
    size_t xb_off   = alloc((size_t)B * CAP * 16);        // cbox
    size_t lb_off   = alloc((size_t)B * CAP * 4);         // ccls

    int* phist  = (int*)(ws + ph_off);
    int* gbs    = (int*)(ws + bs_off);
    int* gbe    = (int*)(ws + be_off);
    int* cnt    = (int*)(ws + cnt_off);
    u64* ckey   = (u64*)(ws + kk_off);
    float4* cbox = (float4*)(ws + xb_off);
    int* ccls   = (int*)(ws + lb_off);

    hist_kernel<<<dim3(HB, B), 1024, 0, stream>>>(pA, pB, N, phist);
    collect_kernel<<<dim3(HB, B), 1024, 0, stream>>>(pA, pB, boxes, N, phist,
                                                     gbs, gbe, cnt, ckey, cbox, ccls);
    finish_kernel<<<B, 1024, 0, stream>>>(cnt, ckey, cbox, ccls, gbs, gbe, out, B);
}